// Round 3
// baseline (282.974 us; speedup 1.0000x reference)
//
#include <hip/hip_runtime.h>

// FlyHash-style sparse projection + per-row exact top-k threshold.
//
// Round 3: attack the DS pipe. Round 2 (passed, bit-exact) spent ~51us in
// random-bank ds_read_b32 gathers (SQ_LDS_BANK_CONFLICT 2e7). Fix: process
// ROWS=4 batch rows per block with the input tile TRANSPOSED in LDS
// (float4 per feature = the 4 rows' values). One ds_read_b128 per (feature,
// index) serves 4 rows: 4x fewer DS instructions, and b128's inherent
// 8-accesses-per-bank smooths the random-bank penalty. Per-component serial
// ascending fold-left is preserved -> x still BIT-MATCHES the reference.
// Histogram: 1024 bins over [4,6) (threshold ~4.8), only v>=4 binned (~10%
// of elements, 10x fewer LDS atomics); key (v-4)*512 is EXACT (Sterbenz +
// pow2 scale). bstar=-1 fallback keeps correctness distribution-free.

typedef float f4 __attribute__((ext_vector_type(4)));

constexpr int IN_F   = 512;
constexpr int OUT_F  = 10240;
constexpr int TPB    = 512;
constexpr int ROWS   = 4;                 // batch rows per block
constexpr int FPT    = OUT_F / TPB;       // 20 features per thread
constexpr int NBINS  = 1024;              // per-row bins over [4,6), width 1/512
constexpr int CHUNK  = 8;
constexpr int NCHUNK = NBINS / CHUNK;     // 128 chunks per row
constexpr int NWAVES = TPB / 64;          // 8

static_assert(ROWS * NCHUNK == TPB, "scan assumes one chunk per thread");

// ---------------------------------------------------------------------------
// Kernel 1: extract sparse indices from dense W. One wave per W row.
// Emits indices ASCENDING (required for bit-exact fold-left downstream).
// ---------------------------------------------------------------------------
__global__ __launch_bounds__(256) void extract_idx(const float* __restrict__ W,
                                                   uint4* __restrict__ packed,
                                                   int out_f) {
  int row  = blockIdx.x * 4 + (threadIdx.x >> 6);
  int lane = threadIdx.x & 63;
  if (row >= out_f) return;

  const float* wr = W + (size_t)row * IN_F;
  unsigned long long masks[8];
#pragma unroll
  for (int c = 0; c < 8; ++c) {
    float v = wr[c * 64 + lane];
    masks[c] = __ballot(v != 0.0f);   // entries are exactly 0.0 or 1.0
  }
  if (lane == 0) {
    unsigned idx[6] = {IN_F, IN_F, IN_F, IN_F, IN_F, IN_F};  // pad -> zero slot
    int n = 0;
#pragma unroll
    for (int c = 0; c < 8; ++c) {
      unsigned long long m = masks[c];
      while (m && n < 6) {
        int b = __builtin_ctzll(m);
        idx[n++] = (unsigned)(c * 64 + b);
        m &= m - 1;
      }
    }
    uint4 r;
    r.x = idx[0] | (idx[1] << 16);
    r.y = idx[2] | (idx[3] << 16);
    r.z = idx[4] | (idx[5] << 16);
    r.w = (unsigned)n;
    packed[row] = r;
  }
}

// ---------------------------------------------------------------------------
// Kernel 2: 4 batch rows per block: compute x (f4 lanes = rows), exact
// per-row top-k thresholds, thresholded writes.
// ---------------------------------------------------------------------------
__global__ __launch_bounds__(TPB, 4) void fly_hash(const float* __restrict__ inp,
                                                   const uint4* __restrict__ packed,
                                                   const int* __restrict__ kptr,
                                                   float* __restrict__ out) {
  __shared__ f4  in4[IN_F + 1];        // [IN_F] = zero slot for pad indices
  __shared__ int hist[ROWS * NBINS];   // 16 KB
  __shared__ int csum[TPB];
  __shared__ int wsum[NWAVES][ROWS];
  __shared__ int sh_bstar[ROWS];

  const int tid  = threadIdx.x;
  const int row0 = blockIdx.x * ROWS;
  const int k    = *kptr;              // hash_length (32)

  // --- stage 4 input rows transposed into LDS ---------------------------
  {
    const float* p = inp + (size_t)row0 * IN_F + tid;
    f4 v;
    v.x = p[0];
    v.y = p[IN_F];
    v.z = p[2 * IN_F];
    v.w = p[3 * IN_F];
    in4[tid] = v;                      // ds_write_b128, stride-1, conflict-free
  }
  if (tid == 0) { f4 z = {0.0f, 0.0f, 0.0f, 0.0f}; in4[IN_F] = z; }
  if (tid < ROWS) sh_bstar[tid] = -1;
  for (int i = tid; i < ROWS * NBINS; i += TPB) hist[i] = 0;
  __syncthreads();

  // --- compute x (bit-exact serial fold-left per component) + histogram --
  f4 x4[FPT];
#pragma unroll
  for (int i = 0; i < FPT; ++i) {
    uint4 r = packed[tid + i * TPB];
    f4 s = in4[r.x & 0xFFFFu];         // ds_read_b128: 4 rows per gather
    s += in4[r.x >> 16];
    s += in4[r.y & 0xFFFFu];
    s += in4[r.y >> 16];
    s += in4[r.z & 0xFFFFu];
    s += in4[r.z >> 16];
    x4[i] = s;
#pragma unroll
    for (int r2 = 0; r2 < ROWS; ++r2) {
      float v = (r2 == 0) ? s.x : (r2 == 1) ? s.y : (r2 == 2) ? s.z : s.w;
      if (v >= 4.0f) {                 // top-32 of 10240 is ~4.8; bin >=4 only
        int b = (int)((v - 4.0f) * 512.0f);   // EXACT key for v in [4,8)
        b = b > NBINS - 1 ? NBINS - 1 : b;
        atomicAdd(&hist[r2 * NBINS + b], 1);
      }
    }
  }
  __syncthreads();

  // --- per-row bracket bin via suffix scan (4 rows in one 512-thread scan)
  {
    const int r = tid >> 7;            // row
    const int c = tid & (NCHUNK - 1);  // chunk within row
    const int base = r * NBINS + c * CHUNK;
    int ssum = 0;
#pragma unroll
    for (int j = 0; j < CHUNK; ++j) ssum += hist[base + j];
    csum[tid] = ssum;
    __syncthreads();
    for (int st = 1; st < NCHUNK; st <<= 1) {
      int v = csum[tid] + ((c + st < NCHUNK) ? csum[tid + st] : 0);
      __syncthreads();
      csum[tid] = v;
      __syncthreads();
    }
    int above = (c + 1 < NCHUNK) ? csum[tid + 1] : 0;
    if (csum[tid] >= k && above < k) {       // unique crossing chunk (if any)
      int acc = above;
      int bsel = c * CHUNK;
      for (int b = c * CHUNK + CHUNK - 1; b >= c * CHUNK; --b) {
        acc += hist[r * NBINS + b];
        if (acc >= k) { bsel = b; break; }
      }
      sh_bstar[r] = bsel;
    }
  }
  __syncthreads();

  // --- exact thresholds: 4 simultaneous bit-level binary searches --------
  // Non-negative f32: uint order == value order. Find max u with
  // count(x >= u) >= k. Bin edges 4+b/512 are exactly representable.
  unsigned lo[ROWS], hi[ROWS];
#pragma unroll
  for (int r = 0; r < ROWS; ++r) {
    int b = sh_bstar[r];
    if (b < 0) {                       // <k values >= 4.0 (distribution-free guard)
      lo[r] = 0u;
      hi[r] = __float_as_uint(4.0f + (1.0f / 512.0f));
    } else {
      lo[r] = __float_as_uint(4.0f + (float)b * (1.0f / 512.0f));
      hi[r] = __float_as_uint(4.0f + (float)(b + 1) * (1.0f / 512.0f));
    }
  }
  const int lane = tid & 63;
  const int wid  = tid >> 6;
  while (lo[0] < hi[0] || lo[1] < hi[1] || lo[2] < hi[2] || lo[3] < hi[3]) {
    unsigned mid[ROWS];
    float fm[ROWS];
#pragma unroll
    for (int r = 0; r < ROWS; ++r) {
      mid[r] = lo[r] + ((hi[r] - lo[r] + 1u) >> 1);
      fm[r] = __uint_as_float(mid[r]);
    }
    int c0 = 0, c1 = 0, c2 = 0, c3 = 0;
#pragma unroll
    for (int i = 0; i < FPT; ++i) {
      c0 += (int)__popcll(__ballot(x4[i].x >= fm[0]));
      c1 += (int)__popcll(__ballot(x4[i].y >= fm[1]));
      c2 += (int)__popcll(__ballot(x4[i].z >= fm[2]));
      c3 += (int)__popcll(__ballot(x4[i].w >= fm[3]));
    }
    if (lane == 0) {
      wsum[wid][0] = c0; wsum[wid][1] = c1; wsum[wid][2] = c2; wsum[wid][3] = c3;
    }
    __syncthreads();
    int tot[ROWS] = {0, 0, 0, 0};
#pragma unroll
    for (int w = 0; w < NWAVES; ++w)
#pragma unroll
      for (int r = 0; r < ROWS; ++r) tot[r] += wsum[w][r];
#pragma unroll
    for (int r = 0; r < ROWS; ++r) {
      if (lo[r] < hi[r]) {
        if (tot[r] >= k) lo[r] = mid[r]; else hi[r] = mid[r] - 1u;
      }
    }
    __syncthreads();
  }
  const float t0 = __uint_as_float(lo[0]);
  const float t1 = __uint_as_float(lo[1]);
  const float t2 = __uint_as_float(lo[2]);
  const float t3 = __uint_as_float(lo[3]);

  // --- thresholded writes, 4 coalesced streams ---------------------------
  float* o0 = out + (size_t)(row0 + 0) * OUT_F;
  float* o1 = out + (size_t)(row0 + 1) * OUT_F;
  float* o2 = out + (size_t)(row0 + 2) * OUT_F;
  float* o3 = out + (size_t)(row0 + 3) * OUT_F;
#pragma unroll
  for (int i = 0; i < FPT; ++i) {
    int f = tid + i * TPB;
    f4 v = x4[i];
    o0[f] = (v.x >= t0) ? v.x : 0.0f;
    o1[f] = (v.y >= t1) ? v.y : 0.0f;
    o2[f] = (v.z >= t2) ? v.z : 0.0f;
    o3[f] = (v.w >= t3) ? v.w : 0.0f;
  }
}

// ---------------------------------------------------------------------------
extern "C" void kernel_launch(void* const* d_in, const int* in_sizes, int n_in,
                              void* d_out, int out_size, void* d_ws, size_t ws_size,
                              hipStream_t stream) {
  const float* inp = (const float*)d_in[0];
  const float* W   = (const float*)d_in[1];
  const int* kptr  = (const int*)d_in[2];
  float* out       = (float*)d_out;

  const int batch = in_sizes[0] / IN_F;   // 4096
  const int out_f = in_sizes[1] / IN_F;   // 10240

  uint4* packed = (uint4*)d_ws;           // 10240 * 16 B = 160 KB scratch

  hipLaunchKernelGGL(extract_idx, dim3((out_f + 3) / 4), dim3(256), 0, stream,
                     W, packed, out_f);
  hipLaunchKernelGGL(fly_hash, dim3(batch / ROWS), dim3(TPB), 0, stream,
                     inp, packed, kptr, out);
}

// Round 4
// 248.250 us; speedup vs baseline: 1.1399x; 1.1399x over previous
//
#include <hip/hip_runtime.h>

// FlyHash-style sparse projection + per-row exact top-k threshold.
//
// Round 4. Round 3 regressed (124us vs round 2's 98us): x4[20] (80 VGPR)
// forced AGPR spills (VGPR_Count=64 + ~64 AGPR -> occupancy 40%). Fixes:
//  - ROWS=2, float2 LDS gathers (ds_read_b64 + v_pk_add_f32): half of round
//    2's DS instruction count, x2[20] = 40 VGPR -> no spill, full occupancy.
//  - Replace the 13-iter block-wide ballot binary search with exact bin-list
//    selection: bracket bin (width 1/512) holds ~1-4 values; append them to
//    an LDS list, one wave rank-selects the (k-above)-th largest. Binary
//    search kept only as an (effectively never-taken) overflow fallback.
//  - Nontemporal output stores (168 MB streaming, no reuse).
// Bit-exactness: per-component serial f32 fold-left in ascending index
// order == ref's einsum accumulation; threshold is an actual x value's bit
// pattern -> mask identical to ref.

typedef float f2 __attribute__((ext_vector_type(2)));

constexpr int IN_F   = 512;
constexpr int OUT_F  = 10240;
constexpr int TPB    = 512;
constexpr int ROWS   = 2;                 // batch rows per block
constexpr int FPT    = OUT_F / TPB;       // 20 features per thread
constexpr int NBINS  = 1024;              // per-row bins over [4,6), width 1/512
constexpr int CHUNK  = 8;
constexpr int NCHUNK = NBINS / CHUNK;     // 128 chunks per row
constexpr int NWAVES = TPB / 64;          // 8
constexpr int CAP    = 64;                // bin-list capacity per row

// ---------------------------------------------------------------------------
// Kernel 1: extract sparse indices from dense W. One wave per W row.
// Emits indices ASCENDING (required for bit-exact fold-left downstream).
// ---------------------------------------------------------------------------
__global__ __launch_bounds__(256) void extract_idx(const float* __restrict__ W,
                                                   uint4* __restrict__ packed,
                                                   int out_f) {
  int row  = blockIdx.x * 4 + (threadIdx.x >> 6);
  int lane = threadIdx.x & 63;
  if (row >= out_f) return;

  const float* wr = W + (size_t)row * IN_F;
  unsigned long long masks[8];
#pragma unroll
  for (int c = 0; c < 8; ++c) {
    float v = wr[c * 64 + lane];
    masks[c] = __ballot(v != 0.0f);   // entries are exactly 0.0 or 1.0
  }
  if (lane == 0) {
    unsigned idx[6] = {IN_F, IN_F, IN_F, IN_F, IN_F, IN_F};  // pad -> zero slot
    int n = 0;
#pragma unroll
    for (int c = 0; c < 8; ++c) {
      unsigned long long m = masks[c];
      while (m && n < 6) {
        int b = __builtin_ctzll(m);
        idx[n++] = (unsigned)(c * 64 + b);
        m &= m - 1;
      }
    }
    uint4 r;
    r.x = idx[0] | (idx[1] << 16);
    r.y = idx[2] | (idx[3] << 16);
    r.z = idx[4] | (idx[5] << 16);
    r.w = (unsigned)n;
    packed[row] = r;
  }
}

// ---------------------------------------------------------------------------
// Kernel 2: 2 batch rows per block.
// ---------------------------------------------------------------------------
__global__ __launch_bounds__(TPB, 4) void fly_hash(const float* __restrict__ inp,
                                                   const uint4* __restrict__ packed,
                                                   const int* __restrict__ kptr,
                                                   float* __restrict__ out) {
  __shared__ f2    in2[IN_F + 1];       // [IN_F] = zero slot for pad indices
  __shared__ int   hist[ROWS * NBINS];  // 8 KB
  __shared__ int   csum[ROWS * NCHUNK]; // 1 KB
  __shared__ int   wsum[NWAVES][ROWS];
  __shared__ int   sh_bstar[ROWS], sh_above[ROWS], sh_n[ROWS], sh_cnt[ROWS];
  __shared__ float sh_list[ROWS][CAP];
  __shared__ float sh_thr[ROWS];
  __shared__ int   sh_need[ROWS];       // 1 -> fallback binary search

  const int tid  = threadIdx.x;
  const int row0 = blockIdx.x * ROWS;
  const int k    = *kptr;               // hash_length (32)

  // --- stage 2 input rows transposed into LDS ---------------------------
  {
    const float* p = inp + (size_t)row0 * IN_F + tid;
    f2 v;
    v.x = p[0];
    v.y = p[IN_F];
    in2[tid] = v;                       // ds_write_b64, conflict-free
  }
  if (tid == 0) { f2 z = {0.0f, 0.0f}; in2[IN_F] = z; }
  if (tid < ROWS) { sh_bstar[tid] = -1; sh_cnt[tid] = 0; }
  for (int i = tid; i < ROWS * NBINS; i += TPB) hist[i] = 0;
  __syncthreads();

  // --- compute x (bit-exact serial fold-left per component) + histogram --
  f2 x2[FPT];
#pragma unroll
  for (int i = 0; i < FPT; ++i) {
    uint4 r = packed[tid + i * TPB];
    f2 s = in2[r.x & 0xFFFFu];          // ds_read_b64: 2 rows per gather
    s += in2[r.x >> 16];
    s += in2[r.y & 0xFFFFu];
    s += in2[r.y >> 16];
    s += in2[r.z & 0xFFFFu];
    s += in2[r.z >> 16];
    x2[i] = s;
    if (s.x >= 4.0f) {                  // top-32 of 10240 ~ 4.8; bin >=4 only
      int b = (int)((s.x - 4.0f) * 512.0f);    // EXACT key (Sterbenz + pow2)
      b = b > NBINS - 1 ? NBINS - 1 : b;
      atomicAdd(&hist[b], 1);
    }
    if (s.y >= 4.0f) {
      int b = (int)((s.y - 4.0f) * 512.0f);
      b = b > NBINS - 1 ? NBINS - 1 : b;
      atomicAdd(&hist[NBINS + b], 1);
    }
  }
  __syncthreads();

  // --- per-row bracket bin via suffix scan over 128 chunks/row -----------
  {
    const bool active = tid < ROWS * NCHUNK;   // 256 threads
    const int r = tid >> 7;            // row (0..1) when active
    const int c = tid & (NCHUNK - 1);  // chunk within row
    if (active) {
      const int base = r * NBINS + c * CHUNK;
      int ssum = 0;
#pragma unroll
      for (int j = 0; j < CHUNK; ++j) ssum += hist[base + j];
      csum[tid] = ssum;
    }
    __syncthreads();
    for (int st = 1; st < NCHUNK; st <<= 1) {
      int v = 0;
      if (active) v = csum[tid] + ((c + st < NCHUNK) ? csum[tid + st] : 0);
      __syncthreads();
      if (active) csum[tid] = v;
      __syncthreads();
    }
    if (active) {
      int above_chunk = (c + 1 < NCHUNK) ? csum[tid + 1] : 0;
      if (csum[tid] >= k && above_chunk < k) {   // unique crossing chunk
        int acc = above_chunk;
        int bsel = c * CHUNK, abv = above_chunk;
        for (int b = c * CHUNK + CHUNK - 1; b >= c * CHUNK; --b) {
          int h = hist[r * NBINS + b];
          if (acc + h >= k) { bsel = b; abv = acc; break; }
          acc += h;
        }
        sh_bstar[r] = bsel;
        sh_above[r] = abv;
        sh_n[r]     = hist[r * NBINS + bsel];
      }
    }
  }
  __syncthreads();

  // --- collect bracket-bin members into per-row lists --------------------
  {
    const int b0 = sh_bstar[0], b1 = sh_bstar[1];
#pragma unroll
    for (int i = 0; i < FPT; ++i) {
      f2 s = x2[i];
      if (s.x >= 4.0f) {
        int b = (int)((s.x - 4.0f) * 512.0f);
        b = b > NBINS - 1 ? NBINS - 1 : b;
        if (b == b0) {
          int p = atomicAdd(&sh_cnt[0], 1);
          if (p < CAP) sh_list[0][p] = s.x;
        }
      }
      if (s.y >= 4.0f) {
        int b = (int)((s.y - 4.0f) * 512.0f);
        b = b > NBINS - 1 ? NBINS - 1 : b;
        if (b == b1) {
          int p = atomicAdd(&sh_cnt[1], 1);
          if (p < CAP) sh_list[1][p] = s.y;
        }
      }
    }
  }
  __syncthreads();

  // --- exact selection: wave r rank-selects the j-th largest in its list --
  {
    const int wid  = tid >> 6;
    const int lane = tid & 63;
    if (wid < ROWS) {
      const int r = wid;
      const int bst = sh_bstar[r];
      const int n   = (bst >= 0) ? sh_n[r] : CAP + 1;
      if (bst >= 0 && n <= CAP) {
        const int j = k - sh_above[r];          // 1 <= j <= n
        float vl = (lane < n) ? sh_list[r][lane] : -1.0f;
        int c_gt = 0, c_ge = 0;
        for (int m = 0; m < n; ++m) {
          float u = sh_list[r][m];              // broadcast read
          c_gt += (u > vl);
          c_ge += (u >= vl);
        }
        if (lane < n && c_gt < j && c_ge >= j) sh_thr[r] = vl;  // exact bits
        if (lane == 0) sh_need[r] = 0;
      } else {
        if (lane == 0) sh_need[r] = 1;          // overflow / no bracket
      }
    }
  }
  __syncthreads();

  // --- fallback: bit-level binary search (normally skipped) --------------
  unsigned lo[ROWS], hi[ROWS];
#pragma unroll
  for (int r = 0; r < ROWS; ++r) {
    if (sh_need[r]) {
      int b = sh_bstar[r];
      if (b < 0) {
        lo[r] = 0u;
        hi[r] = __float_as_uint(4.0f + (1.0f / 512.0f));
      } else {
        lo[r] = __float_as_uint(4.0f + (float)b * (1.0f / 512.0f));
        hi[r] = __float_as_uint(4.0f + (float)(b + 1) * (1.0f / 512.0f));
      }
    } else {
      lo[r] = hi[r] = 0u;
    }
  }
  {
    const int lane = tid & 63;
    const int wid  = tid >> 6;
    while (lo[0] < hi[0] || lo[1] < hi[1]) {
      unsigned mid[ROWS];
      float fm[ROWS];
#pragma unroll
      for (int r = 0; r < ROWS; ++r) {
        mid[r] = lo[r] + ((hi[r] - lo[r] + 1u) >> 1);
        fm[r] = __uint_as_float(mid[r]);
      }
      int c0 = 0, c1 = 0;
#pragma unroll
      for (int i = 0; i < FPT; ++i) {
        c0 += (int)__popcll(__ballot(x2[i].x >= fm[0]));
        c1 += (int)__popcll(__ballot(x2[i].y >= fm[1]));
      }
      if (lane == 0) { wsum[wid][0] = c0; wsum[wid][1] = c1; }
      __syncthreads();
      int tot[ROWS] = {0, 0};
#pragma unroll
      for (int w = 0; w < NWAVES; ++w) {
        tot[0] += wsum[w][0];
        tot[1] += wsum[w][1];
      }
#pragma unroll
      for (int r = 0; r < ROWS; ++r) {
        if (lo[r] < hi[r]) {
          if (tot[r] >= k) lo[r] = mid[r]; else hi[r] = mid[r] - 1u;
        }
      }
      __syncthreads();
    }
  }
  const float t0 = sh_need[0] ? __uint_as_float(lo[0]) : sh_thr[0];
  const float t1 = sh_need[1] ? __uint_as_float(lo[1]) : sh_thr[1];

  // --- thresholded writes, 2 coalesced nontemporal streams ---------------
  float* o0 = out + (size_t)(row0 + 0) * OUT_F;
  float* o1 = out + (size_t)(row0 + 1) * OUT_F;
#pragma unroll
  for (int i = 0; i < FPT; ++i) {
    int f = tid + i * TPB;
    f2 v = x2[i];
    __builtin_nontemporal_store((v.x >= t0) ? v.x : 0.0f, &o0[f]);
    __builtin_nontemporal_store((v.y >= t1) ? v.y : 0.0f, &o1[f]);
  }
}

// ---------------------------------------------------------------------------
extern "C" void kernel_launch(void* const* d_in, const int* in_sizes, int n_in,
                              void* d_out, int out_size, void* d_ws, size_t ws_size,
                              hipStream_t stream) {
  const float* inp = (const float*)d_in[0];
  const float* W   = (const float*)d_in[1];
  const int* kptr  = (const int*)d_in[2];
  float* out       = (float*)d_out;

  const int batch = in_sizes[0] / IN_F;   // 4096
  const int out_f = in_sizes[1] / IN_F;   // 10240

  uint4* packed = (uint4*)d_ws;           // 10240 * 16 B = 160 KB scratch

  hipLaunchKernelGGL(extract_idx, dim3((out_f + 3) / 4), dim3(256), 0, stream,
                     W, packed, out_f);
  hipLaunchKernelGGL(fly_hash, dim3(batch / ROWS), dim3(TPB), 0, stream,
                     inp, packed, kptr, out);
}